// Round 3
// baseline (113.540 us; speedup 1.0000x reference)
//
#include <hip/hip_runtime.h>
#include <hip/hip_fp16.h>

#define BATCH 32
#define TLEN  4096
#define CH    128      // C == F == 128
#define KW    3
#define DIL   8

#define BM    64                 // output rows per block
#define HROWS (BM + 2 * DIL)     // 80  h rows needed
#define XROWS (BM + 4 * DIL)     // 96  x rows needed
#define LDSC  132                // padded row length (f16), 264B stride

typedef _Float16 f16x8 __attribute__((ext_vector_type(8)));
typedef float    f32x4 __attribute__((ext_vector_type(4)));

// ---------------------------------------------------------------------------
// Prep: Wt[j][f][c] = (f16) W[c][j][f]   for both layers' kernels.
// W is (C, K, F) row-major: W[c*KW*CH + j*CH + f].
// ---------------------------------------------------------------------------
__global__ void prep_weights_kernel(const float* __restrict__ W1,
                                    const float* __restrict__ W2,
                                    _Float16* __restrict__ Wt1,
                                    _Float16* __restrict__ Wt2) {
    const int total = KW * CH * CH;
    int idx = blockIdx.x * 256 + threadIdx.x;
    if (idx >= 2 * total) return;
    const float* W  = (idx < total) ? W1 : W2;
    _Float16*    Wt = (idx < total) ? Wt1 : Wt2;
    int r = idx % total;
    int j = r / (CH * CH);
    int f = (r / CH) % CH;
    int c = r % CH;
    Wt[j * CH * CH + f * CH + c] = (_Float16)W[c * (KW * CH) + j * CH + f];
}

// ---------------------------------------------------------------------------
// Fused TemporalDeConvBlock (one block = 64 output rows of one batch):
//   h[u,f]  = relu( sum_{j,c} x[u+(2-j)*D, c] W1[c,j,f] + nv(u)*128*b1[f] )
//   o[t,f]  = relu( relu( sum_{j,c} h[t+(2-j)*D, c] W2[c,j,f] + nv(t)*128*b2[f] ) + x[t,f] )
// Weights for each GEMM are fully prefetched into registers so the MFMA
// K-loops are pure LDS+MFMA (no global-latency serialization).
// 256 threads = 4 waves, n-split: wave w owns cols [32w, 32w+32).
// ---------------------------------------------------------------------------
__global__ __launch_bounds__(256, 3)
void fused_deconv_kernel(const float* __restrict__ x,
                         const _Float16* __restrict__ Wt1,
                         const float* __restrict__ bias1,
                         const _Float16* __restrict__ Wt2,
                         const float* __restrict__ bias2,
                         float* __restrict__ out)
{
    __shared__ __align__(16) _Float16 xs[XROWS][LDSC];   // 96*132*2 = 25344 B
    __shared__ __align__(16) _Float16 hs[HROWS][LDSC];   // 80*132*2 = 21120 B

    const int tid  = threadIdx.x;
    const int lane = tid & 63;
    const int wid  = tid >> 6;
    const int l15  = lane & 15;
    const int kg   = lane >> 4;        // 0..3
    const int nc   = wid << 5;         // wave column base: 0,32,64,96

    const int bt = blockIdx.x;
    const int b  = bt >> 6;            // TLEN/BM = 64 tiles per batch
    const int t0 = (bt & 63) << 6;

    // ---- prefetch ALL GEMM1 weight fragments into registers (24 x 16B).
    // Issued first so their L2 latency overlaps the x HBM staging below.
    f16x8 w1[12][2];
#pragma unroll
    for (int ks = 0; ks < 12; ++ks) {
        const int j  = ks >> 2;
        const int c0 = (ks & 3) << 5;
        const _Float16* wb = Wt1 + (size_t)j * (CH * CH) + c0 + kg * 8;
        w1[ks][0] = *(const f16x8*)(wb + (nc + l15) * CH);
        w1[ks][1] = *(const f16x8*)(wb + (nc + 16 + l15) * CH);
    }

    // ---- stage x window (f32 -> f16), rows t0..t0+XROWS-1, zero past TLEN
    for (int i = tid; i < XROWS * 16; i += 256) {
        const int row = i >> 4;
        const int c8  = (i & 15) << 3;
        const int t   = t0 + row;
        f16x8 o;
        if (t < TLEN) {
            const float* xp = x + ((size_t)b * TLEN + t) * CH + c8;
            f32x4 v0 = *(const f32x4*)(xp + 0);
            f32x4 v1 = *(const f32x4*)(xp + 4);
            o[0] = (_Float16)v0[0]; o[1] = (_Float16)v0[1];
            o[2] = (_Float16)v0[2]; o[3] = (_Float16)v0[3];
            o[4] = (_Float16)v1[0]; o[5] = (_Float16)v1[1];
            o[6] = (_Float16)v1[2]; o[7] = (_Float16)v1[3];
        } else {
            o = (f16x8){};
        }
        *(f16x8*)&xs[row][c8] = o;
    }

    // per-wave bias (col f = nc + n*16 + l15)
    const float bv1_0 = 128.0f * bias1[nc + l15];
    const float bv1_1 = 128.0f * bias1[nc + 16 + l15];
    const float bv2_0 = 128.0f * bias2[nc + l15];
    const float bv2_1 = 128.0f * bias2[nc + 16 + l15];

    __syncthreads();

    // ---- GEMM1: h window rows 0..HROWS-1, cols [nc, nc+32)  (LDS+MFMA only)
    f32x4 acc1[5][2];
#pragma unroll
    for (int m = 0; m < 5; ++m) {
        acc1[m][0] = (f32x4){0.f, 0.f, 0.f, 0.f};
        acc1[m][1] = (f32x4){0.f, 0.f, 0.f, 0.f};
    }
#pragma unroll
    for (int ks = 0; ks < 12; ++ks) {
        const int j     = ks >> 2;
        const int c0    = (ks & 3) << 5;
        const int shift = (2 - j) * DIL;
#pragma unroll
        for (int m = 0; m < 5; ++m) {
            f16x8 af = *(const f16x8*)&xs[m * 16 + shift + l15][c0 + kg * 8];
            acc1[m][0] = __builtin_amdgcn_mfma_f32_16x16x32_f16(af, w1[ks][0], acc1[m][0], 0, 0, 0);
            acc1[m][1] = __builtin_amdgcn_mfma_f32_16x16x32_f16(af, w1[ks][1], acc1[m][1], 0, 0, 0);
        }
    }

    // ---- prefetch ALL GEMM2 weight fragments; latency hides under the
    // hs-store + barrier below (w1 is dead here, registers recycle).
    f16x8 w2[12][2];
#pragma unroll
    for (int ks = 0; ks < 12; ++ks) {
        const int j  = ks >> 2;
        const int c0 = (ks & 3) << 5;
        const _Float16* wb = Wt2 + (size_t)j * (CH * CH) + c0 + kg * 8;
        w2[ks][0] = *(const f16x8*)(wb + (nc + l15) * CH);
        w2[ks][1] = *(const f16x8*)(wb + (nc + 16 + l15) * CH);
    }

    // ---- store h window to LDS (relu + bias; rows past TLEN are zero)
#pragma unroll
    for (int m = 0; m < 5; ++m) {
#pragma unroll
        for (int n = 0; n < 2; ++n) {
            const float bv = (n == 0) ? bv1_0 : bv1_1;
            const int f = nc + n * 16 + l15;
#pragma unroll
            for (int i = 0; i < 4; ++i) {
                const int r = m * 16 + kg * 4 + i;
                const int u = t0 + r;
                const int nv = 1 + (u < TLEN - DIL) + (u < TLEN - 2 * DIL);
                float v = acc1[m][n][i] + (float)nv * bv;
                v = fmaxf(v, 0.0f);
                hs[r][f] = (u < TLEN) ? (_Float16)v : (_Float16)0.0f;
            }
        }
    }
    __syncthreads();

    // ---- GEMM2: out rows 0..BM-1, cols [nc, nc+32)  (LDS+MFMA only)
    f32x4 acc2[4][2];
#pragma unroll
    for (int m = 0; m < 4; ++m) {
        acc2[m][0] = (f32x4){0.f, 0.f, 0.f, 0.f};
        acc2[m][1] = (f32x4){0.f, 0.f, 0.f, 0.f};
    }
#pragma unroll
    for (int ks = 0; ks < 12; ++ks) {
        const int j     = ks >> 2;
        const int shift = (2 - j) * DIL;
        const int c0    = (ks & 3) << 5;
#pragma unroll
        for (int m = 0; m < 4; ++m) {
            f16x8 af = *(const f16x8*)&hs[m * 16 + shift + l15][c0 + kg * 8];
            acc2[m][0] = __builtin_amdgcn_mfma_f32_16x16x32_f16(af, w2[ks][0], acc2[m][0], 0, 0, 0);
            acc2[m][1] = __builtin_amdgcn_mfma_f32_16x16x32_f16(af, w2[ks][1], acc2[m][1], 0, 0, 0);
        }
    }

    // ---- epilogue: bias2 + relu, + residual (from staged f16 x), relu, store f32
#pragma unroll
    for (int m = 0; m < 4; ++m) {
#pragma unroll
        for (int n = 0; n < 2; ++n) {
            const float bv = (n == 0) ? bv2_0 : bv2_1;
            const int f = nc + n * 16 + l15;
#pragma unroll
            for (int i = 0; i < 4; ++i) {
                const int r = m * 16 + kg * 4 + i;
                const int t = t0 + r;
                const int nv = 1 + (t < TLEN - DIL) + (t < TLEN - 2 * DIL);
                float v = acc2[m][n][i] + (float)nv * bv;
                v = fmaxf(v, 0.0f);
                v = v + (float)xs[r][f];
                v = fmaxf(v, 0.0f);
                out[((size_t)b * TLEN + t) * CH + f] = v;
            }
        }
    }
}

// ---------------------------------------------------------------------------
extern "C" void kernel_launch(void* const* d_in, const int* in_sizes, int n_in,
                              void* d_out, int out_size, void* d_ws, size_t ws_size,
                              hipStream_t stream) {
    const float* x  = (const float*)d_in[0];
    const float* W1 = (const float*)d_in[1];
    const float* b1 = (const float*)d_in[2];
    const float* W2 = (const float*)d_in[3];
    const float* b2 = (const float*)d_in[4];
    float* out = (float*)d_out;

    // workspace: Wt1 (3*128*128 f16) | Wt2
    _Float16* Wt1 = (_Float16*)d_ws;
    _Float16* Wt2 = Wt1 + KW * CH * CH;

    prep_weights_kernel<<<(2 * KW * CH * CH + 255) / 256, 256, 0, stream>>>(W1, W2, Wt1, Wt2);

    const int grid = BATCH * (TLEN / BM);   // 2048 blocks
    fused_deconv_kernel<<<grid, 256, 0, stream>>>(x, Wt1, b1, Wt2, b2, out);
}

// Round 4
// 71.571 us; speedup vs baseline: 1.5864x; 1.5864x over previous
//
#include <hip/hip_runtime.h>
#include <hip/hip_fp16.h>

#define BATCH 32
#define TLEN  4096
#define CH    128      // C == F == 128
#define KW    3
#define DIL   8

#define BM    64                 // output rows per block
#define HROWS (BM + 2 * DIL)     // 80  h rows needed
#define XROWS (BM + 4 * DIL)     // 96  x rows needed
#define LDSC  132                // padded row length (f16), 264B stride

typedef _Float16 f16x8 __attribute__((ext_vector_type(8)));
typedef float    f32x4 __attribute__((ext_vector_type(4)));

// ---------------------------------------------------------------------------
// Prep: Wt[j][f][c] = (f16) W[c][j][f]   for both layers' kernels.
// W is (C, K, F) row-major: W[c*KW*CH + j*CH + f].
// ---------------------------------------------------------------------------
__global__ void prep_weights_kernel(const float* __restrict__ W1,
                                    const float* __restrict__ W2,
                                    _Float16* __restrict__ Wt1,
                                    _Float16* __restrict__ Wt2) {
    const int total = KW * CH * CH;
    int idx = blockIdx.x * 256 + threadIdx.x;
    if (idx >= 2 * total) return;
    const float* W  = (idx < total) ? W1 : W2;
    _Float16*    Wt = (idx < total) ? Wt1 : Wt2;
    int r = idx % total;
    int j = r / (CH * CH);
    int f = (r / CH) % CH;
    int c = r % CH;
    Wt[j * CH * CH + f * CH + c] = (_Float16)W[c * (KW * CH) + j * CH + f];
}

// ---------------------------------------------------------------------------
// Fused TemporalDeConvBlock, 512 threads = 8 waves, wave w owns cols
// [16w, 16w+16). Per-wave weight slice for the ACTIVE layer lives in
// registers (12 x f16x8 = 48 VGPRs), so both MFMA K-loops are pure
// LDS+MFMA. Only one layer's weights are live at a time -> fits the
// 128-VGPR cap of __launch_bounds__(512,4) -> 2 blocks/CU (50% occ).
// ---------------------------------------------------------------------------
__global__ __launch_bounds__(512, 4)
void fused_deconv_kernel(const float* __restrict__ x,
                         const _Float16* __restrict__ Wt1,
                         const float* __restrict__ bias1,
                         const _Float16* __restrict__ Wt2,
                         const float* __restrict__ bias2,
                         float* __restrict__ out)
{
    __shared__ __align__(16) _Float16 xs[XROWS][LDSC];   // 96*132*2 = 25344 B
    __shared__ __align__(16) _Float16 hs[HROWS][LDSC];   // 80*132*2 = 21120 B

    const int tid  = threadIdx.x;
    const int lane = tid & 63;
    const int wid  = tid >> 6;         // 0..7
    const int l15  = lane & 15;
    const int kg   = lane >> 4;        // 0..3
    const int nc   = wid << 4;         // wave column base: 0,16,...,112

    const int bt = blockIdx.x;
    const int b  = bt >> 6;            // TLEN/BM = 64 tiles per batch
    const int t0 = (bt & 63) << 6;

    // ---- prefetch GEMM1 weight fragments (12 x 16B = 48 VGPRs).
    // Issued first so their L2 latency overlaps the x HBM staging below.
    f16x8 w1[12];
#pragma unroll
    for (int ks = 0; ks < 12; ++ks) {
        const int j  = ks >> 2;
        const int c0 = (ks & 3) << 5;
        w1[ks] = *(const f16x8*)(Wt1 + (size_t)j * (CH * CH)
                                 + (nc + l15) * CH + c0 + kg * 8);
    }

    // ---- stage x window (f32 -> f16), rows t0..t0+XROWS-1, zero past TLEN
    for (int i = tid; i < XROWS * 16; i += 512) {
        const int row = i >> 4;
        const int c8  = (i & 15) << 3;
        const int t   = t0 + row;
        f16x8 o;
        if (t < TLEN) {
            const float* xp = x + ((size_t)b * TLEN + t) * CH + c8;
            f32x4 v0 = *(const f32x4*)(xp + 0);
            f32x4 v1 = *(const f32x4*)(xp + 4);
            o[0] = (_Float16)v0[0]; o[1] = (_Float16)v0[1];
            o[2] = (_Float16)v0[2]; o[3] = (_Float16)v0[3];
            o[4] = (_Float16)v1[0]; o[5] = (_Float16)v1[1];
            o[6] = (_Float16)v1[2]; o[7] = (_Float16)v1[3];
        } else {
            o = (f16x8){};
        }
        *(f16x8*)&xs[row][c8] = o;
    }

    const float bv1 = 128.0f * bias1[nc + l15];
    const float bv2 = 128.0f * bias2[nc + l15];

    __syncthreads();

    // ---- GEMM1: h rows 0..HROWS-1, cols [nc, nc+16)  (pure LDS+MFMA)
    f32x4 acc1[5];
#pragma unroll
    for (int m = 0; m < 5; ++m) acc1[m] = (f32x4){0.f, 0.f, 0.f, 0.f};
#pragma unroll
    for (int ks = 0; ks < 12; ++ks) {
        const int j     = ks >> 2;
        const int c0    = (ks & 3) << 5;
        const int shift = (2 - j) * DIL;
#pragma unroll
        for (int m = 0; m < 5; ++m) {
            f16x8 af = *(const f16x8*)&xs[m * 16 + shift + l15][c0 + kg * 8];
            acc1[m] = __builtin_amdgcn_mfma_f32_16x16x32_f16(af, w1[ks], acc1[m], 0, 0, 0);
        }
    }

    // ---- prefetch GEMM2 weights (w1 registers recycle); latency hides
    // under the hs-store + barrier below.
    f16x8 w2[12];
#pragma unroll
    for (int ks = 0; ks < 12; ++ks) {
        const int j  = ks >> 2;
        const int c0 = (ks & 3) << 5;
        w2[ks] = *(const f16x8*)(Wt2 + (size_t)j * (CH * CH)
                                 + (nc + l15) * CH + c0 + kg * 8);
    }

    // ---- store h window to LDS (relu + bias; rows past TLEN are zero)
    {
        const int f = nc + l15;
#pragma unroll
        for (int m = 0; m < 5; ++m) {
#pragma unroll
            for (int i = 0; i < 4; ++i) {
                const int r = m * 16 + kg * 4 + i;
                const int u = t0 + r;
                const int nv = 1 + (u < TLEN - DIL) + (u < TLEN - 2 * DIL);
                float v = acc1[m][i] + (float)nv * bv1;
                v = fmaxf(v, 0.0f);
                hs[r][f] = (u < TLEN) ? (_Float16)v : (_Float16)0.0f;
            }
        }
    }
    __syncthreads();

    // ---- GEMM2: out rows 0..BM-1, cols [nc, nc+16)  (pure LDS+MFMA)
    f32x4 acc2[4];
#pragma unroll
    for (int m = 0; m < 4; ++m) acc2[m] = (f32x4){0.f, 0.f, 0.f, 0.f};
#pragma unroll
    for (int ks = 0; ks < 12; ++ks) {
        const int j     = ks >> 2;
        const int c0    = (ks & 3) << 5;
        const int shift = (2 - j) * DIL;
#pragma unroll
        for (int m = 0; m < 4; ++m) {
            f16x8 af = *(const f16x8*)&hs[m * 16 + shift + l15][c0 + kg * 8];
            acc2[m] = __builtin_amdgcn_mfma_f32_16x16x32_f16(af, w2[ks], acc2[m], 0, 0, 0);
        }
    }

    // ---- epilogue: bias2 + relu, + residual (staged f16 x), relu, store f32
    {
        const int f = nc + l15;
#pragma unroll
        for (int m = 0; m < 4; ++m) {
#pragma unroll
            for (int i = 0; i < 4; ++i) {
                const int r = m * 16 + kg * 4 + i;
                const int t = t0 + r;
                const int nv = 1 + (t < TLEN - DIL) + (t < TLEN - 2 * DIL);
                float v = acc2[m][i] + (float)nv * bv2;
                v = fmaxf(v, 0.0f);
                v = v + (float)xs[r][f];
                v = fmaxf(v, 0.0f);
                out[((size_t)b * TLEN + t) * CH + f] = v;
            }
        }
    }
}

// ---------------------------------------------------------------------------
extern "C" void kernel_launch(void* const* d_in, const int* in_sizes, int n_in,
                              void* d_out, int out_size, void* d_ws, size_t ws_size,
                              hipStream_t stream) {
    const float* x  = (const float*)d_in[0];
    const float* W1 = (const float*)d_in[1];
    const float* b1 = (const float*)d_in[2];
    const float* W2 = (const float*)d_in[3];
    const float* b2 = (const float*)d_in[4];
    float* out = (float*)d_out;

    // workspace: Wt1 (3*128*128 f16) | Wt2
    _Float16* Wt1 = (_Float16*)d_ws;
    _Float16* Wt2 = Wt1 + KW * CH * CH;

    prep_weights_kernel<<<(2 * KW * CH * CH + 255) / 256, 256, 0, stream>>>(W1, W2, Wt1, Wt2);

    const int grid = BATCH * (TLEN / BM);   // 2048 blocks
    fused_deconv_kernel<<<grid, 512, 0, stream>>>(x, Wt1, b1, Wt2, b2, out);
}